// Round 17
// baseline (332.555 us; speedup 1.0000x reference)
//
#include <hip/hip_runtime.h>
#include <hip/hip_bf16.h>
#include <math.h>

#define D64 64
#define KTAB 4096          // nearest-neighbor table intervals over r in [0,5]
#define TROWS (KTAB + 1)   // 4097 rows
#define CHUNK 8192         // edges per partition chunk
#define PARTB 196          // k_ptab: blocks in the partition role (ceil(E/CHUNK))
#define TABB 387           // k_ptab: blocks in the tables role (3*129)

typedef unsigned int uint4a __attribute__((ext_vector_type(4), aligned(4)));
typedef __attribute__((ext_vector_type(8))) short bf16x8;   // 8 bf16 (4 VGPRs)
typedef __attribute__((ext_vector_type(4))) float f32x4;    // MFMA C/D frag

// ---------------- helpers ----------------
__device__ __forceinline__ void atomAddF(float* p, float v) {
  __hip_atomic_fetch_add(p, v, __ATOMIC_RELAXED, __HIP_MEMORY_SCOPE_AGENT);
}
__device__ __forceinline__ float swishf(float x) { return x / (1.0f + expf(-x)); }
__device__ __forceinline__ float bx(unsigned short s) {
  return __uint_as_float((unsigned)s << 16);
}
// fp32 -> bf16 bits, round-to-nearest-even (finite inputs)
__device__ __forceinline__ unsigned short f2b(float f) {
  unsigned u = __float_as_uint(f);
  return (unsigned short)((u + 0x7FFFu + ((u >> 16) & 1u)) >> 16);
}

// In-block GraphNorm finalize (replaces the k_nfin launch; every consumer
// block computes it redundantly in a FIXED order -> deterministic and
// bit-identical to the old k_nfin).  Results: snorm[0..63]=scale,
// snorm[64..127]=shift.  partIn==NULL -> identity (layer 0).
__device__ __forceinline__ void normReduce(const float* __restrict__ partIn,
                                           const float* __restrict__ al,
                                           const float* __restrict__ ga,
                                           const float* __restrict__ be,
                                           int n, float* sred, float* snorm) {
  const int t = threadIdx.x;
  if (partIn == nullptr) {
    if (t < 64) { snorm[t] = 1.0f; snorm[64 + t] = 0.0f; }
    __syncthreads();
    return;
  }
  if (t < 128) {
    float s = 0.0f;
#pragma unroll 8
    for (int b = 0; b < 64; ++b) s += partIn[b * 128 + t];
    sred[t] = s;
  }
  __syncthreads();
  if (t < 64) {
    float invN = 1.0f / (float)n;
    float mu = sred[t] * invN;
    float ex2 = sred[64 + t] * invN;
    float a = al[t];
    float var = ex2 - (2.0f * a - a * a) * mu * mu;
    float sc = ga[t] * rsqrtf(var + 1e-5f);
    snorm[t] = sc;
    snorm[64 + t] = be[t] - sc * a * mu;
  }
  __syncthreads();
}

// Fused pre-pass (independent roles split by blockIdx):
//   [0, nbInit)          : feat[i,d] = emb[z[i],d]
//   [nbInit, +18)        : weight prep -> bf16 MFMA fragment layout
//   [nbInit+18, +256)    : 64-bin bucket histogram of dst>>10
__global__ __launch_bounds__(256) void k_pre(const int* __restrict__ z,
                                             const float* __restrict__ emb,
                                             float* __restrict__ feat,
                                             const float* __restrict__ Win,
                                             const float* __restrict__ Wo1,
                                             const float* __restrict__ Wo2,
                                             unsigned short* __restrict__ Wb,
                                             const int* __restrict__ dst,
                                             int* __restrict__ bcnt,
                                             int total, int nbInit, int E) {
  __shared__ int c[64];
  const int bid = blockIdx.x;
  if (bid < nbInit) {
    int idx = bid * 256 + threadIdx.x;
    if (idx < total) feat[idx] = emb[z[idx >> 6] * D64 + (idx & 63)];
  } else if (bid < nbInit + 18) {
    int idx = (bid - nbInit) * 256 + threadIdx.x;   // 3*3*64*8 = 4608
    if (idx < 3 * 3 * 64 * 8) {
      const int fr = idx & 7;
      const int lane = (idx >> 3) & 63;
      const int m = (idx >> 9) % 3;
      const int l = idx / 1536;
      const int ct = fr >> 1, ks = fr & 1;
      const int cc = ct * 16 + (lane & 15);
      const int k0 = ks * 32 + (lane >> 4) * 8;
      const float* W = (m == 0 ? Win : (m == 1 ? Wo1 : Wo2)) + (size_t)l * D64 * D64;
      unsigned short* o = &Wb[(size_t)((l * 3 + m) * 64 + lane) * 64 + fr * 8];
#pragma unroll
      for (int j = 0; j < 8; ++j) o[j] = f2b(W[(k0 + j) * D64 + cc]);
    }
  } else {
    const int hb = bid - nbInit - 18;               // 0..255
    if (threadIdx.x < 64) c[threadIdx.x] = 0;
    __syncthreads();
    const int step = 256 * 256 * 4;
    for (int i = (hb * 256 + threadIdx.x) * 4; i < E; i += step) {
      if (i + 4 <= E) {
        int4 d = *(const int4*)&dst[i];
        atomicAdd(&c[d.x >> 10], 1);
        atomicAdd(&c[d.y >> 10], 1);
        atomicAdd(&c[d.z >> 10], 1);
        atomicAdd(&c[d.w >> 10], 1);
      } else {
        for (int q = i; q < E; ++q) atomicAdd(&c[dst[q] >> 10], 1);
      }
    }
    __syncthreads();
    if (threadIdx.x < 64 && c[threadIdx.x] > 0)
      atomicAdd(&bcnt[threadIdx.x], c[threadIdx.x]);
  }
}

struct PartS {
  uint2 ord[CHUNK];
  int cnt[64], cbase[64], cpos[64], gpos[64], sbase[64];
  int tot;
  unsigned char obk[CHUNK];
};
struct TabS {
  float w1[25 * D64];
  float w2[D64 * D64];
  float rb[16][D64];
};

// Fused: blocks [0,PARTB) = CSR phase-1 counting-sort partition (8192-edge
// chunks, 1024 threads);  blocks [PARTB, PARTB+TABB) = bf16 filter table.
// The 64-bucket exclusive scan is computed IN-BLOCK from bcnt (k_scan64
// removed); global reservation counters start at 0 (memset).
__global__ __launch_bounds__(1024) void k_ptab(const int* __restrict__ src,
                                               const int* __restrict__ dst,
                                               const float* __restrict__ rij,
                                               const int* __restrict__ bcnt,
                                               int* __restrict__ gcur,
                                               uint2* __restrict__ rec, int E,
                                               const float* __restrict__ Wf1,
                                               const float* __restrict__ bf1,
                                               const float* __restrict__ Wf2,
                                               const float* __restrict__ bf2,
                                               __hip_bfloat16* __restrict__ Tb) {
  __shared__ __align__(16) char smem[sizeof(PartS) > sizeof(TabS) ? sizeof(PartS)
                                                                  : sizeof(TabS)];
  const int tid = threadIdx.x;
  if (blockIdx.x < PARTB) {
    PartS& S = *(PartS*)smem;
    if (tid < 64) {
      int v = bcnt[tid];
      int x = v;
      for (int o = 1; o < 64; o <<= 1) {
        int y = __shfl_up(x, o);
        if (tid >= o) x += y;
      }
      S.sbase[tid] = x - v;
    }
    __syncthreads();
    for (int c = blockIdx.x; (size_t)c * CHUNK < (size_t)E; c += PARTB) {
      const int s0 = c * CHUNK;
      if (tid < 64) S.cnt[tid] = 0;
      __syncthreads();
      const int i0 = s0 + tid * 8;
      int dd[8], ss[8];
      float rr[8];
      bool val[8];
      if (i0 + 8 <= E) {
        int4 d0 = *(const int4*)&dst[i0];
        int4 d1 = *(const int4*)&dst[i0 + 4];
        int4 sa = *(const int4*)&src[i0];
        int4 sb2 = *(const int4*)&src[i0 + 4];
        float4 r0 = *(const float4*)&rij[i0];
        float4 r1 = *(const float4*)&rij[i0 + 4];
        dd[0] = d0.x; dd[1] = d0.y; dd[2] = d0.z; dd[3] = d0.w;
        dd[4] = d1.x; dd[5] = d1.y; dd[6] = d1.z; dd[7] = d1.w;
        ss[0] = sa.x; ss[1] = sa.y; ss[2] = sa.z; ss[3] = sa.w;
        ss[4] = sb2.x; ss[5] = sb2.y; ss[6] = sb2.z; ss[7] = sb2.w;
        rr[0] = r0.x; rr[1] = r0.y; rr[2] = r0.z; rr[3] = r0.w;
        rr[4] = r1.x; rr[5] = r1.y; rr[6] = r1.z; rr[7] = r1.w;
#pragma unroll
        for (int q = 0; q < 8; ++q) val[q] = true;
      } else {
#pragma unroll
        for (int q = 0; q < 8; ++q) {
          int i = i0 + q;
          val[q] = (i < E);
          if (val[q]) { dd[q] = dst[i]; ss[q] = src[i]; rr[q] = rij[i]; }
          else { dd[q] = 0; ss[q] = 0; rr[q] = 0.0f; }
        }
      }
      int bk[8];
      unsigned ry[8];
#pragma unroll
      for (int q = 0; q < 8; ++q) {
        bk[q] = dd[q] >> 10;
        int k = (int)(rr[q] * ((float)KTAB * 0.2f) + 0.5f);
        if (k > KTAB) k = KTAB;
        ry[q] = ((unsigned)ss[q] << 16) | (unsigned)k;
        if (val[q]) atomicAdd(&S.cnt[bk[q]], 1);
      }
      __syncthreads();
      if (tid < 64) {
        int v = S.cnt[tid];
        int x = v;
        for (int o = 1; o < 64; o <<= 1) {
          int y = __shfl_up(x, o);
          if (tid >= o) x += y;
        }
        S.cbase[tid] = x - v;
        S.cpos[tid] = x - v;
        if (tid == 63) S.tot = x;
      }
      __syncthreads();
#pragma unroll
      for (int q = 0; q < 8; ++q) {
        if (val[q]) {
          int slot = atomicAdd(&S.cpos[bk[q]], 1);
          S.ord[slot] = make_uint2((unsigned)dd[q], ry[q]);
          S.obk[slot] = (unsigned char)bk[q];
        }
      }
      __syncthreads();
      if (tid < 64 && S.cnt[tid] > 0)
        S.gpos[tid] = S.sbase[tid] + atomicAdd(&gcur[tid * 16], S.cnt[tid]);
      __syncthreads();
      const int tot = S.tot;
      for (int t = tid; t < tot; t += 1024) {
        int b2 = S.obk[t];
        rec[S.gpos[b2] + (t - S.cbase[b2])] = S.ord[t];
      }
      __syncthreads();
    }
  } else {
    TabS& T = *(TabS*)smem;
    const int tb = blockIdx.x - PARTB;
    const int lane = tid & 63;
    const int wsl = tid >> 6;            // 0..15
    const int l = tb / 129;
    const int gb = tb % 129;
    for (int i = tid; i < 25 * D64; i += 1024) T.w1[i] = Wf1[l * 25 * D64 + i];
    for (int i = tid; i < D64 * D64; i += 1024) T.w2[i] = Wf2[l * D64 * D64 + i];
    __syncthreads();
    const float bias1 = bf1[l * D64 + lane];
    const float bias2 = bf2[l * D64 + lane];
    const float width = 5.0f / 24.0f;
    const float coeff = -0.5f / (width * width);
    for (int gi = 0; gi < 2; ++gi) {
      const int g = gb * 32 + wsl * 2 + gi;
      if (g >= TROWS) break;
      const float r = (float)g * (5.0f / KTAB);
      float fv = 0.0f;
      if (lane < 25) { float ddv = r - (float)lane * width; fv = expf(coeff * ddv * ddv); }
      T.rb[wsl][lane] = fv;   // same-wave LDS reuse; program order preserves deps
      float a1 = bias1;
#pragma unroll
      for (int b = 0; b < 25; ++b)
        a1 = fmaf(T.rb[wsl][b], T.w1[b * D64 + lane], a1);
      float sw = swishf(a1);
      T.rb[wsl][lane] = sw;
      float a2 = bias2;
#pragma unroll
      for (int k = 0; k < D64; ++k)
        a2 = fmaf(T.rb[wsl][k], T.w2[k * D64 + lane], a2);
      float C = (r < 5.0f) ? 0.5f * (cosf(r * 0.62831853f) + 1.0f) : 0.0f;
      Tb[(size_t)(l * TROWS + g) * D64 + lane] = __float2bfloat16(a2 * C);
    }
  }
}

// CSR phase 2: one 1024-thread block per bucket; in-block bucket scan from
// bcnt; LDS histogram + scan -> rp, LDS-atomic cursors -> ep.
__global__ __launch_bounds__(1024) void k_build(const uint2* __restrict__ rec,
                                                const int* __restrict__ bcnt,
                                                int* __restrict__ rp,
                                                unsigned* __restrict__ ep, int n) {
  __shared__ int cnt[1024];
  __shared__ int curl[1024];
  __shared__ int sb2[65];
  const int tid = threadIdx.x;
  const int b = blockIdx.x;
  if (tid < 64) {
    int v = bcnt[tid];
    int x = v;
    for (int o = 1; o < 64; o <<= 1) {
      int y = __shfl_up(x, o);
      if (tid >= o) x += y;
    }
    sb2[tid] = x - v;
    if (tid == 63) sb2[64] = x;
  }
  cnt[tid] = 0;
  __syncthreads();
  const int lo = sb2[b], hi = sb2[b + 1];
  for (int i = lo + tid; i < hi; i += 1024)
    atomicAdd(&cnt[rec[i].x & 1023], 1);
  __syncthreads();
  const int v = cnt[tid];
  for (int o = 1; o < 1024; o <<= 1) {
    int t = (tid >= o) ? cnt[tid - o] : 0;
    __syncthreads();
    cnt[tid] += t;
    __syncthreads();
  }
  const int excl = cnt[tid] - v;
  curl[tid] = excl;
  const int node = (b << 10) + tid;
  if (node <= n) rp[node] = lo + excl;
  __syncthreads();
  for (int i = lo + tid; i < hi; i += 1024) {
    uint2 e = rec[i];
    int pos = lo + atomicAdd(&curl[e.x & 1023], 1);
    ep[pos] = e.y;
  }
}

// x1 = bf16(norm(feat) @ Win) via MFMA.  Prev-layer norm computed in-block
// from partIn (k_nfin launch removed); weights pre-converted (Wb).
__global__ __launch_bounds__(256) void k_x1(const float* __restrict__ feat,
                                            const unsigned short* __restrict__ Wb,
                                            const float* __restrict__ partIn,
                                            const float* __restrict__ al,
                                            const float* __restrict__ ga,
                                            const float* __restrict__ be,
                                            __hip_bfloat16* __restrict__ x1, int n) {
  __shared__ float sred[128];
  __shared__ float snorm[128];
  normReduce(partIn, al, ga, be, n, sred, snorm);
  const int lane = threadIdx.x & 63;
  const int r16 = lane & 15;
  const int kg = lane >> 4;
  unsigned short* __restrict__ x1u = (unsigned short*)x1;
  const unsigned short* wl = Wb + (size_t)lane * 64;
  bf16x8 bw[4][2];
#pragma unroll
  for (int ct = 0; ct < 4; ++ct)
#pragma unroll
    for (int ks = 0; ks < 2; ++ks)
      bw[ct][ks] = *(const bf16x8*)&wl[(ct * 2 + ks) * 8];
  float sca[2][8], sha[2][8];
#pragma unroll
  for (int ks = 0; ks < 2; ++ks) {
    const int k0 = ks * 32 + kg * 8;
#pragma unroll
    for (int j = 0; j < 8; ++j) {
      sca[ks][j] = snorm[k0 + j];
      sha[ks][j] = snorm[64 + k0 + j];
    }
  }
  const int ntile = (n + 15) >> 4;
  const int wid = (blockIdx.x * blockDim.x + threadIdx.x) >> 6;
  const int nw = (gridDim.x * blockDim.x) >> 6;
  for (int t = wid; t < ntile; t += nw) {
    const int base = t * 16;
    int ra = base + r16; if (ra > n - 1) ra = n - 1;
    bf16x8 a[2];
#pragma unroll
    for (int ks = 0; ks < 2; ++ks) {
      const float* p = &feat[(size_t)ra * D64 + ks * 32 + kg * 8];
      bf16x8 v;
#pragma unroll
      for (int j = 0; j < 8; ++j) v[j] = (short)f2b(fmaf(p[j], sca[ks][j], sha[ks][j]));
      a[ks] = v;
    }
    f32x4 acc[4];
#pragma unroll
    for (int ct = 0; ct < 4; ++ct) {
      f32x4 z = {0.0f, 0.0f, 0.0f, 0.0f};
      z = __builtin_amdgcn_mfma_f32_16x16x32_bf16(a[0], bw[ct][0], z, 0, 0, 0);
      z = __builtin_amdgcn_mfma_f32_16x16x32_bf16(a[1], bw[ct][1], z, 0, 0, 0);
      acc[ct] = z;
    }
#pragma unroll
    for (int ct = 0; ct < 4; ++ct)
#pragma unroll
      for (int r = 0; r < 4; ++r) {
        const int rm = base + kg * 4 + r;
        if (rm < n) x1u[(size_t)rm * D64 + ct * 16 + r16] = f2b(acc[ct][r]);
      }
  }
}

// agg[nd] = bf16( sum over incoming edges of x1[src] * Tb[k] ).
// Half-wave edge pairing; 16-edge main loop (8 per half = 18 loads in flight).
__global__ __launch_bounds__(256) void k_gather(const __hip_bfloat16* __restrict__ x1,
                                                const __hip_bfloat16* __restrict__ Tb,
                                                const unsigned* __restrict__ ep,
                                                const int* __restrict__ rp,
                                                unsigned short* __restrict__ aggb, int n) {
  const int lane = threadIdx.x & 63;
  const int half = lane >> 5;
  const int fl = lane & 31;            // features 2*fl, 2*fl+1
  const unsigned short* __restrict__ x1u = (const unsigned short*)x1;
  const unsigned short* __restrict__ Tu = (const unsigned short*)Tb;
  const int wid = (blockIdx.x * blockDim.x + threadIdx.x) >> 6;
  const int nw = (gridDim.x * blockDim.x) >> 6;
  for (int nd = wid; nd < n; nd += nw) {
    const int j0 = rp[nd], j1 = rp[nd + 1];
    float ax0 = 0.0f, ay0 = 0.0f, ax1 = 0.0f, ay1 = 0.0f;
    int j = j0;
    for (; j + 16 <= j1; j += 16) {
      const uint4a ua = *(const uint4a*)(ep + j + 8 * half);
      const uint4a ub = *(const uint4a*)(ep + j + 8 * half + 4);
      const unsigned u[8] = {ua.x, ua.y, ua.z, ua.w, ub.x, ub.y, ub.z, ub.w};
      ushort2 xv[8], tv[8];
#pragma unroll
      for (int q = 0; q < 8; ++q)
        xv[q] = *(const ushort2*)&x1u[(size_t)(u[q] >> 16) * D64 + fl * 2];
#pragma unroll
      for (int q = 0; q < 8; ++q)
        tv[q] = *(const ushort2*)&Tu[(size_t)(u[q] & 0x1FFFu) * D64 + fl * 2];
#pragma unroll
      for (int q = 0; q < 8; ++q) {
        if (q & 1) {
          ax1 = fmaf(bx(xv[q].x), bx(tv[q].x), ax1);
          ay1 = fmaf(bx(xv[q].y), bx(tv[q].y), ay1);
        } else {
          ax0 = fmaf(bx(xv[q].x), bx(tv[q].x), ax0);
          ay0 = fmaf(bx(xv[q].y), bx(tv[q].y), ay0);
        }
      }
    }
    for (; j + 8 <= j1; j += 8) {
      const uint4a uu = *(const uint4a*)(ep + j + 4 * half);
      const unsigned u0 = uu.x, u1 = uu.y, u2 = uu.z, u3 = uu.w;
      const ushort2 xA = *(const ushort2*)&x1u[(size_t)(u0 >> 16) * D64 + fl * 2];
      const ushort2 xB = *(const ushort2*)&x1u[(size_t)(u1 >> 16) * D64 + fl * 2];
      const ushort2 xC = *(const ushort2*)&x1u[(size_t)(u2 >> 16) * D64 + fl * 2];
      const ushort2 xD = *(const ushort2*)&x1u[(size_t)(u3 >> 16) * D64 + fl * 2];
      const ushort2 tA = *(const ushort2*)&Tu[(size_t)(u0 & 0x1FFFu) * D64 + fl * 2];
      const ushort2 tB = *(const ushort2*)&Tu[(size_t)(u1 & 0x1FFFu) * D64 + fl * 2];
      const ushort2 tC = *(const ushort2*)&Tu[(size_t)(u2 & 0x1FFFu) * D64 + fl * 2];
      const ushort2 tD = *(const ushort2*)&Tu[(size_t)(u3 & 0x1FFFu) * D64 + fl * 2];
      ax0 = fmaf(bx(xA.x), bx(tA.x), ax0);
      ay0 = fmaf(bx(xA.y), bx(tA.y), ay0);
      ax1 = fmaf(bx(xB.x), bx(tB.x), ax1);
      ay1 = fmaf(bx(xB.y), bx(tB.y), ay1);
      ax0 = fmaf(bx(xC.x), bx(tC.x), ax0);
      ay0 = fmaf(bx(xC.y), bx(tC.y), ay0);
      ax1 = fmaf(bx(xD.x), bx(tD.x), ax1);
      ay1 = fmaf(bx(xD.y), bx(tD.y), ay1);
    }
    for (; j + 2 <= j1; j += 2) {
      const unsigned u = ep[j + half];
      const ushort2 xr = *(const ushort2*)&x1u[(size_t)(u >> 16) * D64 + fl * 2];
      const ushort2 tw = *(const ushort2*)&Tu[(size_t)(u & 0x1FFFu) * D64 + fl * 2];
      ax0 = fmaf(bx(xr.x), bx(tw.x), ax0);
      ay0 = fmaf(bx(xr.y), bx(tw.y), ay0);
    }
    if (j < j1 && half == 0) {
      const unsigned u = ep[j];
      const ushort2 xr = *(const ushort2*)&x1u[(size_t)(u >> 16) * D64 + fl * 2];
      const ushort2 tw = *(const ushort2*)&Tu[(size_t)(u & 0x1FFFu) * D64 + fl * 2];
      ax0 = fmaf(bx(xr.x), bx(tw.x), ax0);
      ay0 = fmaf(bx(xr.y), bx(tw.y), ay0);
    }
    float ax = ax0 + ax1, ay = ay0 + ay1;
    ax += __shfl_xor(ax, 32);
    ay += __shfl_xor(ay, 32);
    if (half == 0) {
      unsigned pk = ((unsigned)f2b(ay) << 16) | (unsigned)f2b(ax);
      *(unsigned*)&aggb[(size_t)nd * D64 + fl * 2] = pk;
    }
  }
}

// y = swish(agg@Wo1+bo1)@Wo2+bo2; feat = norm(feat) + y via chained MFMA.
// Prev-layer norm computed in-block from partIn; per-feature sums into
// THIS layer's partOut (own buffer, zeroed upfront -> no k_nfin, no zeroing).
__global__ __launch_bounds__(256) void k_out(const unsigned short* __restrict__ aggb,
                                             const unsigned short* __restrict__ Wb1,
                                             const unsigned short* __restrict__ Wb2,
                                             const float* __restrict__ bo1,
                                             const float* __restrict__ bo2,
                                             const float* __restrict__ partIn,
                                             const float* __restrict__ al,
                                             const float* __restrict__ ga,
                                             const float* __restrict__ be,
                                             float* __restrict__ feat,
                                             float* __restrict__ partOut, int n) {
  __shared__ __align__(16) unsigned short tl[4][16 * 72];
  __shared__ float redp[4][128];
  __shared__ float sred[128];
  __shared__ float snorm[128];
  normReduce(partIn, al, ga, be, n, sred, snorm);
  const int lane = threadIdx.x & 63;
  const int wsl = threadIdx.x >> 6;
  const int r16 = lane & 15;
  const int kg = lane >> 4;
  const unsigned short* wl1 = Wb1 + (size_t)lane * 64;
  const unsigned short* wl2 = Wb2 + (size_t)lane * 64;
  bf16x8 bw1[4][2], bw2[4][2];
#pragma unroll
  for (int ct = 0; ct < 4; ++ct)
#pragma unroll
    for (int ks = 0; ks < 2; ++ks) {
      bw1[ct][ks] = *(const bf16x8*)&wl1[(ct * 2 + ks) * 8];
      bw2[ct][ks] = *(const bf16x8*)&wl2[(ct * 2 + ks) * 8];
    }
  float b1c[4], b2c[4], scc[4], shc[4];
#pragma unroll
  for (int ct = 0; ct < 4; ++ct) {
    b1c[ct] = bo1[ct * 16 + r16];
    b2c[ct] = bo2[ct * 16 + r16];
    scc[ct] = snorm[ct * 16 + r16];
    shc[ct] = snorm[64 + ct * 16 + r16];
  }
  float sf[4] = {0, 0, 0, 0}, sf2[4] = {0, 0, 0, 0};
  unsigned short* tw = tl[wsl];
  const int ntile = (n + 15) >> 4;
  const int wid = (blockIdx.x * blockDim.x + threadIdx.x) >> 6;
  const int nw = (gridDim.x * blockDim.x) >> 6;
  for (int t = wid; t < ntile; t += nw) {
    const int base = t * 16;
    int ra = base + r16; if (ra > n - 1) ra = n - 1;
    bf16x8 a1[2];
#pragma unroll
    for (int ks = 0; ks < 2; ++ks)
      a1[ks] = *(const bf16x8*)&aggb[(size_t)ra * D64 + ks * 32 + kg * 8];
    f32x4 acc[4];
#pragma unroll
    for (int ct = 0; ct < 4; ++ct) {
      f32x4 z = {0.0f, 0.0f, 0.0f, 0.0f};
      z = __builtin_amdgcn_mfma_f32_16x16x32_bf16(a1[0], bw1[ct][0], z, 0, 0, 0);
      z = __builtin_amdgcn_mfma_f32_16x16x32_bf16(a1[1], bw1[ct][1], z, 0, 0, 0);
      acc[ct] = z;
    }
#pragma unroll
    for (int ct = 0; ct < 4; ++ct)
#pragma unroll
      for (int r = 0; r < 4; ++r)
        tw[(kg * 4 + r) * 72 + ct * 16 + r16] = f2b(swishf(acc[ct][r] + b1c[ct]));
    bf16x8 a2[2];
#pragma unroll
    for (int ks = 0; ks < 2; ++ks)
      a2[ks] = *(const bf16x8*)&tw[r16 * 72 + ks * 32 + kg * 8];
    f32x4 acc2[4];
#pragma unroll
    for (int ct = 0; ct < 4; ++ct) {
      f32x4 z = {0.0f, 0.0f, 0.0f, 0.0f};
      z = __builtin_amdgcn_mfma_f32_16x16x32_bf16(a2[0], bw2[ct][0], z, 0, 0, 0);
      z = __builtin_amdgcn_mfma_f32_16x16x32_bf16(a2[1], bw2[ct][1], z, 0, 0, 0);
      acc2[ct] = z;
    }
#pragma unroll
    for (int ct = 0; ct < 4; ++ct)
#pragma unroll
      for (int r = 0; r < 4; ++r) {
        const int rm = base + kg * 4 + r;
        if (rm < n) {
          const size_t ix = (size_t)rm * D64 + ct * 16 + r16;
          float fv = fmaf(feat[ix], scc[ct], shc[ct]);
          float fn = fv + acc2[ct][r] + b2c[ct];
          feat[ix] = fn;
          sf[ct] += fn;
          sf2[ct] += fn * fn;
        }
      }
  }
  // wave reduce over kg (lanes kg*16+r16 share feature ct*16+r16)
#pragma unroll
  for (int ct = 0; ct < 4; ++ct) {
    sf[ct] += __shfl_xor(sf[ct], 16);
    sf[ct] += __shfl_xor(sf[ct], 32);
    sf2[ct] += __shfl_xor(sf2[ct], 16);
    sf2[ct] += __shfl_xor(sf2[ct], 32);
  }
  if (kg == 0) {
#pragma unroll
    for (int ct = 0; ct < 4; ++ct) {
      redp[wsl][ct * 16 + r16] = sf[ct];
      redp[wsl][64 + ct * 16 + r16] = sf2[ct];
    }
  }
  __syncthreads();
  if (threadIdx.x < 128) {
    float v = redp[0][threadIdx.x] + redp[1][threadIdx.x] +
              redp[2][threadIdx.x] + redp[3][threadIdx.x];
    atomAddF(&partOut[(blockIdx.x & 63) * 128 + threadIdx.x], v);
  }
}

// Fused readout: layer-2 norm computed in-block from partIn; apply it
// (materialize normalized feat), accumulate s1 = sum e^(f-20),
// s2 = sum f*e^(f-20) into partOut.
__global__ __launch_bounds__(256) void k_pool(float* __restrict__ feat,
                                              const float* __restrict__ partIn,
                                              const float* __restrict__ al,
                                              const float* __restrict__ ga,
                                              const float* __restrict__ be,
                                              float* __restrict__ partOut, int n) {
  __shared__ float redp[4][128];
  __shared__ float sred[128];
  __shared__ float snorm[128];
  normReduce(partIn, al, ga, be, n, sred, snorm);
  const int lane = threadIdx.x & 63;
  const int wsl = threadIdx.x >> 6;
  const float sc = snorm[lane], sh = snorm[64 + lane];
  float s1 = 0.0f, s2 = 0.0f;
  const int wid = (blockIdx.x * blockDim.x + threadIdx.x) >> 6;
  const int nw = (gridDim.x * blockDim.x) >> 6;
  int base = wid * 4;
  const int stride = nw * 4;
  for (; base + 4 <= n; base += stride) {
    float f0 = feat[(size_t)(base + 0) * D64 + lane];
    float f1 = feat[(size_t)(base + 1) * D64 + lane];
    float f2 = feat[(size_t)(base + 2) * D64 + lane];
    float f3 = feat[(size_t)(base + 3) * D64 + lane];
    f0 = fmaf(f0, sc, sh);
    f1 = fmaf(f1, sc, sh);
    f2 = fmaf(f2, sc, sh);
    f3 = fmaf(f3, sc, sh);
    feat[(size_t)(base + 0) * D64 + lane] = f0;
    feat[(size_t)(base + 1) * D64 + lane] = f1;
    feat[(size_t)(base + 2) * D64 + lane] = f2;
    feat[(size_t)(base + 3) * D64 + lane] = f3;
    float e0 = expf(f0 - 20.0f);
    float e1 = expf(f1 - 20.0f);
    float e2 = expf(f2 - 20.0f);
    float e3 = expf(f3 - 20.0f);
    s1 += (e0 + e1) + (e2 + e3);
    s2 += fmaf(f0, e0, f1 * e1) + fmaf(f2, e2, f3 * e3);
  }
  for (int r = base; r < n; ++r) {
    float f = fmaf(feat[(size_t)r * D64 + lane], sc, sh);
    feat[(size_t)r * D64 + lane] = f;
    float e = expf(f - 20.0f);
    s1 += e;
    s2 += f * e;
  }
  redp[wsl][lane] = s1;
  redp[wsl][64 + lane] = s2;
  __syncthreads();
  if (threadIdx.x < 128) {
    float v = redp[0][threadIdx.x] + redp[1][threadIdx.x] +
              redp[2][threadIdx.x] + redp[3][threadIdx.x];
    atomAddF(&partOut[(blockIdx.x & 63) * 128 + threadIdx.x], v);
  }
}

// final reduce of striped pool partials -> pooled = s2/s1
__global__ void k_pooled(const float* __restrict__ part, float* __restrict__ out) {
  int d = threadIdx.x;  // 64 threads
  float s1 = 0.0f, s2 = 0.0f;
#pragma unroll 8
  for (int b = 0; b < 64; ++b) {
    s1 += part[b * 128 + d];
    s2 += part[b * 128 + 64 + d];
  }
  out[d] = s2 / s1;
}

extern "C" void kernel_launch(void* const* d_in, const int* in_sizes, int n_in,
                              void* d_out, int out_size, void* d_ws, size_t ws_size,
                              hipStream_t stream) {
  const int* z = (const int*)d_in[0];
  const int* src = (const int*)d_in[1];
  const int* dst = (const int*)d_in[2];
  const float* rij = (const float*)d_in[3];
  const float* emb = (const float*)d_in[4];
  const float* Win = (const float*)d_in[5];
  const float* Wf1 = (const float*)d_in[6];
  const float* bf1 = (const float*)d_in[7];
  const float* Wf2 = (const float*)d_in[8];
  const float* bf2 = (const float*)d_in[9];
  const float* Wo1 = (const float*)d_in[10];
  const float* bo1 = (const float*)d_in[11];
  const float* Wo2 = (const float*)d_in[12];
  const float* bo2 = (const float*)d_in[13];
  const float* gal = (const float*)d_in[14];
  const float* gga = (const float*)d_in[15];
  const float* gbe = (const float*)d_in[16];
  const int n = in_sizes[0];
  const int E = in_sizes[1];
  (void)n_in; (void)out_size; (void)ws_size;

  float* feat = (float*)d_out;                 // [n,64] lives in d_out
  float* pooled = feat + (size_t)n * D64;      // [64]

  char* w = (char*)d_ws;
  size_t off = 0;
  auto take = [&](size_t bytes) {
    size_t o = (off + 255) & ~(size_t)255;
    off = o + bytes;
    return (void*)(w + o);
  };
  __hip_bfloat16* x1 = (__hip_bfloat16*)take((size_t)n * D64 * 2);
  size_t aggrec = ((size_t)n * D64 * 2 > (size_t)E * 8) ? (size_t)n * D64 * 2
                                                        : (size_t)E * 8;
  unsigned short* aggb = (unsigned short*)take(aggrec);  // aliased with rec
  uint2* rec = (uint2*)aggb;
  float* part = (float*)take(4 * 64 * 128 * 4);   // 4 buffers: L0,L1,L2,pool
  __hip_bfloat16* Tb = (__hip_bfloat16*)take((size_t)3 * TROWS * D64 * 2);
  unsigned short* Wb = (unsigned short*)take((size_t)9 * 64 * 64 * 2);
  int* rp = (int*)take((size_t)(n + 1) * 4);
  unsigned* ep = (unsigned*)take((size_t)E * 4);
  int* misc = (int*)take((64 + 64 * 16) * 4);  // [0..63]=bcnt, [64..]=gcur (padded)
  int* bcnt = misc;
  int* gcur = misc + 64;

  const int total = n * D64;
  const int nbInit = (total + 255) / 256;

  hipMemsetAsync(misc, 0, (64 + 64 * 16) * 4, stream);
  hipMemsetAsync(part, 0, 4 * 64 * 128 * 4, stream);
  k_pre<<<nbInit + 18 + 256, 256, 0, stream>>>(z, emb, feat, Win, Wo1, Wo2, Wb,
                                               dst, bcnt, total, nbInit, E);
  k_ptab<<<PARTB + TABB, 1024, 0, stream>>>(src, dst, rij, bcnt, gcur, rec, E,
                                            Wf1, bf1, Wf2, bf2, Tb);
  k_build<<<64, 1024, 0, stream>>>(rec, bcnt, rp, ep, n);

  for (int l = 0; l < 3; ++l) {
    const float* pin = (l == 0) ? nullptr : part + (size_t)(l - 1) * 8192;
    const float* al = (l == 0) ? nullptr : gal + (l - 1) * D64;
    const float* ga = (l == 0) ? nullptr : gga + (l - 1) * D64;
    const float* be = (l == 0) ? nullptr : gbe + (l - 1) * D64;
    k_x1<<<784, 256, 0, stream>>>(feat, Wb + (size_t)(l * 3 + 0) * 64 * 64,
                                  pin, al, ga, be, x1, n);
    k_gather<<<2048, 256, 0, stream>>>(x1, Tb + (size_t)l * TROWS * D64,
                                       ep, rp, aggb, n);
    k_out<<<784, 256, 0, stream>>>(aggb,
                                   Wb + (size_t)(l * 3 + 1) * 64 * 64,
                                   Wb + (size_t)(l * 3 + 2) * 64 * 64,
                                   bo1 + l * D64, bo2 + l * D64,
                                   pin, al, ga, be,
                                   feat, part + (size_t)l * 8192, n);
  }

  k_pool<<<1024, 256, 0, stream>>>(feat, part + 2 * 8192,
                                   gal + 2 * D64, gga + 2 * D64, gbe + 2 * D64,
                                   part + 3 * 8192, n);
  k_pooled<<<1, 64, 0, stream>>>(part + 3 * 8192, pooled);
}

// Round 18
// 325.581 us; speedup vs baseline: 1.0214x; 1.0214x over previous
//
#include <hip/hip_runtime.h>
#include <hip/hip_bf16.h>
#include <math.h>

#define D64 64
#define KTAB 4096          // nearest-neighbor table intervals over r in [0,5]
#define TROWS (KTAB + 1)   // 4097 rows
#define CHUNK 8192         // edges per partition chunk
#define PARTB 196          // k_ptab: blocks in the partition role (ceil(E/CHUNK))
#define TABB 387           // k_ptab: blocks in the tables role (3*129)

typedef unsigned int uint4a __attribute__((ext_vector_type(4), aligned(4)));
typedef __attribute__((ext_vector_type(8))) short bf16x8;   // 8 bf16 (4 VGPRs)
typedef __attribute__((ext_vector_type(4))) float f32x4;    // MFMA C/D frag

// ---------------- helpers ----------------
__device__ __forceinline__ void atomAddF(float* p, float v) {
  __hip_atomic_fetch_add(p, v, __ATOMIC_RELAXED, __HIP_MEMORY_SCOPE_AGENT);
}
__device__ __forceinline__ float swishf(float x) { return x / (1.0f + expf(-x)); }
__device__ __forceinline__ float bx(unsigned short s) {
  return __uint_as_float((unsigned)s << 16);
}
// fp32 -> bf16 bits, round-to-nearest-even (finite inputs)
__device__ __forceinline__ unsigned short f2b(float f) {
  unsigned u = __float_as_uint(f);
  return (unsigned short)((u + 0x7FFFu + ((u >> 16) & 1u)) >> 16);
}

// In-block GraphNorm finalize (every consumer block computes it redundantly in
// a FIXED order -> deterministic).  snorm[0..63]=scale, snorm[64..127]=shift.
// partIn==NULL -> identity (layer 0).
__device__ __forceinline__ void normReduce(const float* __restrict__ partIn,
                                           const float* __restrict__ al,
                                           const float* __restrict__ ga,
                                           const float* __restrict__ be,
                                           int n, float* sred, float* snorm) {
  const int t = threadIdx.x;
  if (partIn == nullptr) {
    if (t < 64) { snorm[t] = 1.0f; snorm[64 + t] = 0.0f; }
    __syncthreads();
    return;
  }
  if (t < 128) {
    float s = 0.0f;
#pragma unroll 8
    for (int b = 0; b < 64; ++b) s += partIn[b * 128 + t];
    sred[t] = s;
  }
  __syncthreads();
  if (t < 64) {
    float invN = 1.0f / (float)n;
    float mu = sred[t] * invN;
    float ex2 = sred[64 + t] * invN;
    float a = al[t];
    float var = ex2 - (2.0f * a - a * a) * mu * mu;
    float sc = ga[t] * rsqrtf(var + 1e-5f);
    snorm[t] = sc;
    snorm[64 + t] = be[t] - sc * a * mu;
  }
  __syncthreads();
}

// Fused pre-pass (independent roles split by blockIdx):
//   [0, nbInit)          : feat[i,d] = emb[z[i],d]
//   [nbInit, +18)        : weight prep -> bf16 MFMA fragment layout
//   [nbInit+18, +256)    : 64-bin bucket histogram of dst>>10
__global__ __launch_bounds__(256) void k_pre(const int* __restrict__ z,
                                             const float* __restrict__ emb,
                                             float* __restrict__ feat,
                                             const float* __restrict__ Win,
                                             const float* __restrict__ Wo1,
                                             const float* __restrict__ Wo2,
                                             unsigned short* __restrict__ Wb,
                                             const int* __restrict__ dst,
                                             int* __restrict__ bcnt,
                                             int total, int nbInit, int E) {
  __shared__ int c[64];
  const int bid = blockIdx.x;
  if (bid < nbInit) {
    int idx = bid * 256 + threadIdx.x;
    if (idx < total) feat[idx] = emb[z[idx >> 6] * D64 + (idx & 63)];
  } else if (bid < nbInit + 18) {
    int idx = (bid - nbInit) * 256 + threadIdx.x;   // 3*3*64*8 = 4608
    if (idx < 3 * 3 * 64 * 8) {
      const int fr = idx & 7;
      const int lane = (idx >> 3) & 63;
      const int m = (idx >> 9) % 3;
      const int l = idx / 1536;
      const int ct = fr >> 1, ks = fr & 1;
      const int cc = ct * 16 + (lane & 15);
      const int k0 = ks * 32 + (lane >> 4) * 8;
      const float* W = (m == 0 ? Win : (m == 1 ? Wo1 : Wo2)) + (size_t)l * D64 * D64;
      unsigned short* o = &Wb[(size_t)((l * 3 + m) * 64 + lane) * 64 + fr * 8];
#pragma unroll
      for (int j = 0; j < 8; ++j) o[j] = f2b(W[(k0 + j) * D64 + cc]);
    }
  } else {
    const int hb = bid - nbInit - 18;               // 0..255
    if (threadIdx.x < 64) c[threadIdx.x] = 0;
    __syncthreads();
    const int step = 256 * 256 * 4;
    for (int i = (hb * 256 + threadIdx.x) * 4; i < E; i += step) {
      if (i + 4 <= E) {
        int4 d = *(const int4*)&dst[i];
        atomicAdd(&c[d.x >> 10], 1);
        atomicAdd(&c[d.y >> 10], 1);
        atomicAdd(&c[d.z >> 10], 1);
        atomicAdd(&c[d.w >> 10], 1);
      } else {
        for (int q = i; q < E; ++q) atomicAdd(&c[dst[q] >> 10], 1);
      }
    }
    __syncthreads();
    if (threadIdx.x < 64 && c[threadIdx.x] > 0)
      atomicAdd(&bcnt[threadIdx.x], c[threadIdx.x]);
  }
}

struct PartS {
  uint2 ord[CHUNK];
  int cnt[64], cbase[64], cpos[64], gpos[64], sbase[64];
  int tot;
  unsigned char obk[CHUNK];
};
struct TabS {
  float w1[25 * D64];
  float w2[D64 * D64];
  float rb[16][D64];
};

// Fused: blocks [0,PARTB) = CSR phase-1 counting-sort partition (8192-edge
// chunks, 1024 threads);  blocks [PARTB, PARTB+TABB) = bf16 filter table.
__global__ __launch_bounds__(1024) void k_ptab(const int* __restrict__ src,
                                               const int* __restrict__ dst,
                                               const float* __restrict__ rij,
                                               const int* __restrict__ bcnt,
                                               int* __restrict__ gcur,
                                               uint2* __restrict__ rec, int E,
                                               const float* __restrict__ Wf1,
                                               const float* __restrict__ bf1,
                                               const float* __restrict__ Wf2,
                                               const float* __restrict__ bf2,
                                               __hip_bfloat16* __restrict__ Tb) {
  __shared__ __align__(16) char smem[sizeof(PartS) > sizeof(TabS) ? sizeof(PartS)
                                                                  : sizeof(TabS)];
  const int tid = threadIdx.x;
  if (blockIdx.x < PARTB) {
    PartS& S = *(PartS*)smem;
    if (tid < 64) {
      int v = bcnt[tid];
      int x = v;
      for (int o = 1; o < 64; o <<= 1) {
        int y = __shfl_up(x, o);
        if (tid >= o) x += y;
      }
      S.sbase[tid] = x - v;
    }
    __syncthreads();
    for (int c = blockIdx.x; (size_t)c * CHUNK < (size_t)E; c += PARTB) {
      const int s0 = c * CHUNK;
      if (tid < 64) S.cnt[tid] = 0;
      __syncthreads();
      const int i0 = s0 + tid * 8;
      int dd[8], ss[8];
      float rr[8];
      bool val[8];
      if (i0 + 8 <= E) {
        int4 d0 = *(const int4*)&dst[i0];
        int4 d1 = *(const int4*)&dst[i0 + 4];
        int4 sa = *(const int4*)&src[i0];
        int4 sb2 = *(const int4*)&src[i0 + 4];
        float4 r0 = *(const float4*)&rij[i0];
        float4 r1 = *(const float4*)&rij[i0 + 4];
        dd[0] = d0.x; dd[1] = d0.y; dd[2] = d0.z; dd[3] = d0.w;
        dd[4] = d1.x; dd[5] = d1.y; dd[6] = d1.z; dd[7] = d1.w;
        ss[0] = sa.x; ss[1] = sa.y; ss[2] = sa.z; ss[3] = sa.w;
        ss[4] = sb2.x; ss[5] = sb2.y; ss[6] = sb2.z; ss[7] = sb2.w;
        rr[0] = r0.x; rr[1] = r0.y; rr[2] = r0.z; rr[3] = r0.w;
        rr[4] = r1.x; rr[5] = r1.y; rr[6] = r1.z; rr[7] = r1.w;
#pragma unroll
        for (int q = 0; q < 8; ++q) val[q] = true;
      } else {
#pragma unroll
        for (int q = 0; q < 8; ++q) {
          int i = i0 + q;
          val[q] = (i < E);
          if (val[q]) { dd[q] = dst[i]; ss[q] = src[i]; rr[q] = rij[i]; }
          else { dd[q] = 0; ss[q] = 0; rr[q] = 0.0f; }
        }
      }
      int bk[8];
      unsigned ry[8];
#pragma unroll
      for (int q = 0; q < 8; ++q) {
        bk[q] = dd[q] >> 10;
        int k = (int)(rr[q] * ((float)KTAB * 0.2f) + 0.5f);
        if (k > KTAB) k = KTAB;
        ry[q] = ((unsigned)ss[q] << 16) | (unsigned)k;
        if (val[q]) atomicAdd(&S.cnt[bk[q]], 1);
      }
      __syncthreads();
      if (tid < 64) {
        int v = S.cnt[tid];
        int x = v;
        for (int o = 1; o < 64; o <<= 1) {
          int y = __shfl_up(x, o);
          if (tid >= o) x += y;
        }
        S.cbase[tid] = x - v;
        S.cpos[tid] = x - v;
        if (tid == 63) S.tot = x;
      }
      __syncthreads();
#pragma unroll
      for (int q = 0; q < 8; ++q) {
        if (val[q]) {
          int slot = atomicAdd(&S.cpos[bk[q]], 1);
          S.ord[slot] = make_uint2((unsigned)dd[q], ry[q]);
          S.obk[slot] = (unsigned char)bk[q];
        }
      }
      __syncthreads();
      if (tid < 64 && S.cnt[tid] > 0)
        S.gpos[tid] = S.sbase[tid] + atomicAdd(&gcur[tid * 16], S.cnt[tid]);
      __syncthreads();
      const int tot = S.tot;
      for (int t = tid; t < tot; t += 1024) {
        int b2 = S.obk[t];
        rec[S.gpos[b2] + (t - S.cbase[b2])] = S.ord[t];
      }
      __syncthreads();
    }
  } else {
    TabS& T = *(TabS*)smem;
    const int tb = blockIdx.x - PARTB;
    const int lane = tid & 63;
    const int wsl = tid >> 6;            // 0..15
    const int l = tb / 129;
    const int gb = tb % 129;
    for (int i = tid; i < 25 * D64; i += 1024) T.w1[i] = Wf1[l * 25 * D64 + i];
    for (int i = tid; i < D64 * D64; i += 1024) T.w2[i] = Wf2[l * D64 * D64 + i];
    __syncthreads();
    const float bias1 = bf1[l * D64 + lane];
    const float bias2 = bf2[l * D64 + lane];
    const float width = 5.0f / 24.0f;
    const float coeff = -0.5f / (width * width);
    for (int gi = 0; gi < 2; ++gi) {
      const int g = gb * 32 + wsl * 2 + gi;
      if (g >= TROWS) break;
      const float r = (float)g * (5.0f / KTAB);
      float fv = 0.0f;
      if (lane < 25) { float ddv = r - (float)lane * width; fv = expf(coeff * ddv * ddv); }
      T.rb[wsl][lane] = fv;   // same-wave LDS reuse; program order preserves deps
      float a1 = bias1;
#pragma unroll
      for (int b = 0; b < 25; ++b)
        a1 = fmaf(T.rb[wsl][b], T.w1[b * D64 + lane], a1);
      float sw = swishf(a1);
      T.rb[wsl][lane] = sw;
      float a2 = bias2;
#pragma unroll
      for (int k = 0; k < D64; ++k)
        a2 = fmaf(T.rb[wsl][k], T.w2[k * D64 + lane], a2);
      float C = (r < 5.0f) ? 0.5f * (cosf(r * 0.62831853f) + 1.0f) : 0.0f;
      Tb[(size_t)(l * TROWS + g) * D64 + lane] = __float2bfloat16(a2 * C);
    }
  }
}

// CSR phase 2: 4 blocks per bucket (256 blocks total = full machine; R17
// profile showed the 64-block version at 6% occupancy, 44us, 75% idle).
// Each block owns a 256-node quarter: register-private quarter counts
// (wave-shfl reduced) give the cross-quarter base; 256-entry LDS histogram
// + scan -> rp; LDS cursors -> ep placement (own-quarter records only).
__global__ __launch_bounds__(1024) void k_build(const uint2* __restrict__ rec,
                                                const int* __restrict__ bcnt,
                                                int* __restrict__ rp,
                                                unsigned* __restrict__ ep, int n) {
  __shared__ int cnt[256];
  __shared__ int curl[256];
  __shared__ int sb2[65];
  __shared__ int qcnt[4];
  __shared__ int qoff_s;
  const int tid = threadIdx.x;
  const int bb = blockIdx.x >> 2;
  const int q = blockIdx.x & 3;
  const int lane = tid & 63;
  if (tid < 64) {
    int v = bcnt[tid];
    int x = v;
    for (int o = 1; o < 64; o <<= 1) {
      int y = __shfl_up(x, o);
      if (tid >= o) x += y;
    }
    sb2[tid] = x - v;
    if (tid == 63) sb2[64] = x;
  }
  if (tid < 256) cnt[tid] = 0;
  if (tid < 4) qcnt[tid] = 0;
  __syncthreads();
  const int lo = sb2[bb], hi = sb2[bb + 1];
  // pass 1: own-quarter histogram + private quarter counts
  int qc0 = 0, qc1 = 0, qc2 = 0, qc3 = 0;
  for (int base = lo; base < hi; base += 1024) {
    const int i = base + tid;
    if (i < hi) {
      const int ln = rec[i].x & 1023;
      const int qr = ln >> 8;
      qc0 += (qr == 0);
      qc1 += (qr == 1);
      qc2 += (qr == 2);
      qc3 += (qr == 3);
      if (qr == q) atomicAdd(&cnt[ln & 255], 1);
    }
  }
#pragma unroll
  for (int o = 1; o < 64; o <<= 1) {
    qc0 += __shfl_xor(qc0, o);
    qc1 += __shfl_xor(qc1, o);
    qc2 += __shfl_xor(qc2, o);
    qc3 += __shfl_xor(qc3, o);
  }
  if (lane == 0) {
    if (qc0) atomicAdd(&qcnt[0], qc0);
    if (qc1) atomicAdd(&qcnt[1], qc1);
    if (qc2) atomicAdd(&qcnt[2], qc2);
    if (qc3) atomicAdd(&qcnt[3], qc3);
  }
  __syncthreads();
  if (tid == 0) {
    int s = 0;
    for (int qq = 0; qq < q; ++qq) s += qcnt[qq];
    qoff_s = s;
  }
  __syncthreads();
  // 256-entry exclusive scan
  const int v = (tid < 256) ? cnt[tid] : 0;
  for (int o = 1; o < 256; o <<= 1) {
    int t2 = (tid >= o && tid < 256) ? cnt[tid - o] : 0;
    __syncthreads();
    if (tid < 256) cnt[tid] += t2;
    __syncthreads();
  }
  const int qbase = lo + qoff_s;
  if (tid < 256) {
    const int excl = cnt[tid] - v;
    curl[tid] = excl;
    const int node = (bb << 10) + (q << 8) + tid;
    if (node <= n) rp[node] = qbase + excl;
  }
  __syncthreads();
  // pass 2: place own-quarter records
  for (int base = lo; base < hi; base += 1024) {
    const int i = base + tid;
    if (i < hi) {
      const uint2 e = rec[i];
      const int ln = e.x & 1023;
      if ((ln >> 8) == q) {
        int pos = qbase + atomicAdd(&curl[ln & 255], 1);
        ep[pos] = e.y;
      }
    }
  }
}

// x1 = bf16(norm(feat) @ Win) via MFMA.  Prev-layer norm computed in-block.
__global__ __launch_bounds__(256) void k_x1(const float* __restrict__ feat,
                                            const unsigned short* __restrict__ Wb,
                                            const float* __restrict__ partIn,
                                            const float* __restrict__ al,
                                            const float* __restrict__ ga,
                                            const float* __restrict__ be,
                                            __hip_bfloat16* __restrict__ x1, int n) {
  __shared__ float sred[128];
  __shared__ float snorm[128];
  normReduce(partIn, al, ga, be, n, sred, snorm);
  const int lane = threadIdx.x & 63;
  const int r16 = lane & 15;
  const int kg = lane >> 4;
  unsigned short* __restrict__ x1u = (unsigned short*)x1;
  const unsigned short* wl = Wb + (size_t)lane * 64;
  bf16x8 bw[4][2];
#pragma unroll
  for (int ct = 0; ct < 4; ++ct)
#pragma unroll
    for (int ks = 0; ks < 2; ++ks)
      bw[ct][ks] = *(const bf16x8*)&wl[(ct * 2 + ks) * 8];
  float sca[2][8], sha[2][8];
#pragma unroll
  for (int ks = 0; ks < 2; ++ks) {
    const int k0 = ks * 32 + kg * 8;
#pragma unroll
    for (int j = 0; j < 8; ++j) {
      sca[ks][j] = snorm[k0 + j];
      sha[ks][j] = snorm[64 + k0 + j];
    }
  }
  const int ntile = (n + 15) >> 4;
  const int wid = (blockIdx.x * blockDim.x + threadIdx.x) >> 6;
  const int nw = (gridDim.x * blockDim.x) >> 6;
  for (int t = wid; t < ntile; t += nw) {
    const int base = t * 16;
    int ra = base + r16; if (ra > n - 1) ra = n - 1;
    bf16x8 a[2];
#pragma unroll
    for (int ks = 0; ks < 2; ++ks) {
      const float* p = &feat[(size_t)ra * D64 + ks * 32 + kg * 8];
      bf16x8 v;
#pragma unroll
      for (int j = 0; j < 8; ++j) v[j] = (short)f2b(fmaf(p[j], sca[ks][j], sha[ks][j]));
      a[ks] = v;
    }
    f32x4 acc[4];
#pragma unroll
    for (int ct = 0; ct < 4; ++ct) {
      f32x4 z = {0.0f, 0.0f, 0.0f, 0.0f};
      z = __builtin_amdgcn_mfma_f32_16x16x32_bf16(a[0], bw[ct][0], z, 0, 0, 0);
      z = __builtin_amdgcn_mfma_f32_16x16x32_bf16(a[1], bw[ct][1], z, 0, 0, 0);
      acc[ct] = z;
    }
#pragma unroll
    for (int ct = 0; ct < 4; ++ct)
#pragma unroll
      for (int r = 0; r < 4; ++r) {
        const int rm = base + kg * 4 + r;
        if (rm < n) x1u[(size_t)rm * D64 + ct * 16 + r16] = f2b(acc[ct][r]);
      }
  }
}

// agg[nd] = bf16( sum over incoming edges of x1[src] * Tb[k] ).
// Half-wave edge pairing; 16-edge main loop (8 per half = 18 loads in flight).
__global__ __launch_bounds__(256) void k_gather(const __hip_bfloat16* __restrict__ x1,
                                                const __hip_bfloat16* __restrict__ Tb,
                                                const unsigned* __restrict__ ep,
                                                const int* __restrict__ rp,
                                                unsigned short* __restrict__ aggb, int n) {
  const int lane = threadIdx.x & 63;
  const int half = lane >> 5;
  const int fl = lane & 31;            // features 2*fl, 2*fl+1
  const unsigned short* __restrict__ x1u = (const unsigned short*)x1;
  const unsigned short* __restrict__ Tu = (const unsigned short*)Tb;
  const int wid = (blockIdx.x * blockDim.x + threadIdx.x) >> 6;
  const int nw = (gridDim.x * blockDim.x) >> 6;
  for (int nd = wid; nd < n; nd += nw) {
    const int j0 = rp[nd], j1 = rp[nd + 1];
    float ax0 = 0.0f, ay0 = 0.0f, ax1 = 0.0f, ay1 = 0.0f;
    int j = j0;
    for (; j + 16 <= j1; j += 16) {
      const uint4a ua = *(const uint4a*)(ep + j + 8 * half);
      const uint4a ub = *(const uint4a*)(ep + j + 8 * half + 4);
      const unsigned u[8] = {ua.x, ua.y, ua.z, ua.w, ub.x, ub.y, ub.z, ub.w};
      ushort2 xv[8], tv[8];
#pragma unroll
      for (int q = 0; q < 8; ++q)
        xv[q] = *(const ushort2*)&x1u[(size_t)(u[q] >> 16) * D64 + fl * 2];
#pragma unroll
      for (int q = 0; q < 8; ++q)
        tv[q] = *(const ushort2*)&Tu[(size_t)(u[q] & 0x1FFFu) * D64 + fl * 2];
#pragma unroll
      for (int q = 0; q < 8; ++q) {
        if (q & 1) {
          ax1 = fmaf(bx(xv[q].x), bx(tv[q].x), ax1);
          ay1 = fmaf(bx(xv[q].y), bx(tv[q].y), ay1);
        } else {
          ax0 = fmaf(bx(xv[q].x), bx(tv[q].x), ax0);
          ay0 = fmaf(bx(xv[q].y), bx(tv[q].y), ay0);
        }
      }
    }
    for (; j + 8 <= j1; j += 8) {
      const uint4a uu = *(const uint4a*)(ep + j + 4 * half);
      const unsigned u0 = uu.x, u1 = uu.y, u2 = uu.z, u3 = uu.w;
      const ushort2 xA = *(const ushort2*)&x1u[(size_t)(u0 >> 16) * D64 + fl * 2];
      const ushort2 xB = *(const ushort2*)&x1u[(size_t)(u1 >> 16) * D64 + fl * 2];
      const ushort2 xC = *(const ushort2*)&x1u[(size_t)(u2 >> 16) * D64 + fl * 2];
      const ushort2 xD = *(const ushort2*)&x1u[(size_t)(u3 >> 16) * D64 + fl * 2];
      const ushort2 tA = *(const ushort2*)&Tu[(size_t)(u0 & 0x1FFFu) * D64 + fl * 2];
      const ushort2 tB = *(const ushort2*)&Tu[(size_t)(u1 & 0x1FFFu) * D64 + fl * 2];
      const ushort2 tC = *(const ushort2*)&Tu[(size_t)(u2 & 0x1FFFu) * D64 + fl * 2];
      const ushort2 tD = *(const ushort2*)&Tu[(size_t)(u3 & 0x1FFFu) * D64 + fl * 2];
      ax0 = fmaf(bx(xA.x), bx(tA.x), ax0);
      ay0 = fmaf(bx(xA.y), bx(tA.y), ay0);
      ax1 = fmaf(bx(xB.x), bx(tB.x), ax1);
      ay1 = fmaf(bx(xB.y), bx(tB.y), ay1);
      ax0 = fmaf(bx(xC.x), bx(tC.x), ax0);
      ay0 = fmaf(bx(xC.y), bx(tC.y), ay0);
      ax1 = fmaf(bx(xD.x), bx(tD.x), ax1);
      ay1 = fmaf(bx(xD.y), bx(tD.y), ay1);
    }
    for (; j + 2 <= j1; j += 2) {
      const unsigned u = ep[j + half];
      const ushort2 xr = *(const ushort2*)&x1u[(size_t)(u >> 16) * D64 + fl * 2];
      const ushort2 tw = *(const ushort2*)&Tu[(size_t)(u & 0x1FFFu) * D64 + fl * 2];
      ax0 = fmaf(bx(xr.x), bx(tw.x), ax0);
      ay0 = fmaf(bx(xr.y), bx(tw.y), ay0);
    }
    if (j < j1 && half == 0) {
      const unsigned u = ep[j];
      const ushort2 xr = *(const ushort2*)&x1u[(size_t)(u >> 16) * D64 + fl * 2];
      const ushort2 tw = *(const ushort2*)&Tu[(size_t)(u & 0x1FFFu) * D64 + fl * 2];
      ax0 = fmaf(bx(xr.x), bx(tw.x), ax0);
      ay0 = fmaf(bx(xr.y), bx(tw.y), ay0);
    }
    float ax = ax0 + ax1, ay = ay0 + ay1;
    ax += __shfl_xor(ax, 32);
    ay += __shfl_xor(ay, 32);
    if (half == 0) {
      unsigned pk = ((unsigned)f2b(ay) << 16) | (unsigned)f2b(ax);
      *(unsigned*)&aggb[(size_t)nd * D64 + fl * 2] = pk;
    }
  }
}

// y = swish(agg@Wo1+bo1)@Wo2+bo2; feat = norm(feat) + y via chained MFMA.
__global__ __launch_bounds__(256) void k_out(const unsigned short* __restrict__ aggb,
                                             const unsigned short* __restrict__ Wb1,
                                             const unsigned short* __restrict__ Wb2,
                                             const float* __restrict__ bo1,
                                             const float* __restrict__ bo2,
                                             const float* __restrict__ partIn,
                                             const float* __restrict__ al,
                                             const float* __restrict__ ga,
                                             const float* __restrict__ be,
                                             float* __restrict__ feat,
                                             float* __restrict__ partOut, int n) {
  __shared__ __align__(16) unsigned short tl[4][16 * 72];
  __shared__ float redp[4][128];
  __shared__ float sred[128];
  __shared__ float snorm[128];
  normReduce(partIn, al, ga, be, n, sred, snorm);
  const int lane = threadIdx.x & 63;
  const int wsl = threadIdx.x >> 6;
  const int r16 = lane & 15;
  const int kg = lane >> 4;
  const unsigned short* wl1 = Wb1 + (size_t)lane * 64;
  const unsigned short* wl2 = Wb2 + (size_t)lane * 64;
  bf16x8 bw1[4][2], bw2[4][2];
#pragma unroll
  for (int ct = 0; ct < 4; ++ct)
#pragma unroll
    for (int ks = 0; ks < 2; ++ks) {
      bw1[ct][ks] = *(const bf16x8*)&wl1[(ct * 2 + ks) * 8];
      bw2[ct][ks] = *(const bf16x8*)&wl2[(ct * 2 + ks) * 8];
    }
  float b1c[4], b2c[4], scc[4], shc[4];
#pragma unroll
  for (int ct = 0; ct < 4; ++ct) {
    b1c[ct] = bo1[ct * 16 + r16];
    b2c[ct] = bo2[ct * 16 + r16];
    scc[ct] = snorm[ct * 16 + r16];
    shc[ct] = snorm[64 + ct * 16 + r16];
  }
  float sf[4] = {0, 0, 0, 0}, sf2[4] = {0, 0, 0, 0};
  unsigned short* tw = tl[wsl];
  const int ntile = (n + 15) >> 4;
  const int wid = (blockIdx.x * blockDim.x + threadIdx.x) >> 6;
  const int nw = (gridDim.x * blockDim.x) >> 6;
  for (int t = wid; t < ntile; t += nw) {
    const int base = t * 16;
    int ra = base + r16; if (ra > n - 1) ra = n - 1;
    bf16x8 a1[2];
#pragma unroll
    for (int ks = 0; ks < 2; ++ks)
      a1[ks] = *(const bf16x8*)&aggb[(size_t)ra * D64 + ks * 32 + kg * 8];
    f32x4 acc[4];
#pragma unroll
    for (int ct = 0; ct < 4; ++ct) {
      f32x4 z = {0.0f, 0.0f, 0.0f, 0.0f};
      z = __builtin_amdgcn_mfma_f32_16x16x32_bf16(a1[0], bw1[ct][0], z, 0, 0, 0);
      z = __builtin_amdgcn_mfma_f32_16x16x32_bf16(a1[1], bw1[ct][1], z, 0, 0, 0);
      acc[ct] = z;
    }
#pragma unroll
    for (int ct = 0; ct < 4; ++ct)
#pragma unroll
      for (int r = 0; r < 4; ++r)
        tw[(kg * 4 + r) * 72 + ct * 16 + r16] = f2b(swishf(acc[ct][r] + b1c[ct]));
    bf16x8 a2[2];
#pragma unroll
    for (int ks = 0; ks < 2; ++ks)
      a2[ks] = *(const bf16x8*)&tw[r16 * 72 + ks * 32 + kg * 8];
    f32x4 acc2[4];
#pragma unroll
    for (int ct = 0; ct < 4; ++ct) {
      f32x4 z = {0.0f, 0.0f, 0.0f, 0.0f};
      z = __builtin_amdgcn_mfma_f32_16x16x32_bf16(a2[0], bw2[ct][0], z, 0, 0, 0);
      z = __builtin_amdgcn_mfma_f32_16x16x32_bf16(a2[1], bw2[ct][1], z, 0, 0, 0);
      acc2[ct] = z;
    }
#pragma unroll
    for (int ct = 0; ct < 4; ++ct)
#pragma unroll
      for (int r = 0; r < 4; ++r) {
        const int rm = base + kg * 4 + r;
        if (rm < n) {
          const size_t ix = (size_t)rm * D64 + ct * 16 + r16;
          float fv = fmaf(feat[ix], scc[ct], shc[ct]);
          float fn = fv + acc2[ct][r] + b2c[ct];
          feat[ix] = fn;
          sf[ct] += fn;
          sf2[ct] += fn * fn;
        }
      }
  }
  // wave reduce over kg (lanes kg*16+r16 share feature ct*16+r16)
#pragma unroll
  for (int ct = 0; ct < 4; ++ct) {
    sf[ct] += __shfl_xor(sf[ct], 16);
    sf[ct] += __shfl_xor(sf[ct], 32);
    sf2[ct] += __shfl_xor(sf2[ct], 16);
    sf2[ct] += __shfl_xor(sf2[ct], 32);
  }
  if (kg == 0) {
#pragma unroll
    for (int ct = 0; ct < 4; ++ct) {
      redp[wsl][ct * 16 + r16] = sf[ct];
      redp[wsl][64 + ct * 16 + r16] = sf2[ct];
    }
  }
  __syncthreads();
  if (threadIdx.x < 128) {
    float v = redp[0][threadIdx.x] + redp[1][threadIdx.x] +
              redp[2][threadIdx.x] + redp[3][threadIdx.x];
    atomAddF(&partOut[(blockIdx.x & 63) * 128 + threadIdx.x], v);
  }
}

// Fused readout: layer-2 norm in-block; apply it (materialize normalized
// feat), accumulate s1 = sum e^(f-20), s2 = sum f*e^(f-20) into partOut.
__global__ __launch_bounds__(256) void k_pool(float* __restrict__ feat,
                                              const float* __restrict__ partIn,
                                              const float* __restrict__ al,
                                              const float* __restrict__ ga,
                                              const float* __restrict__ be,
                                              float* __restrict__ partOut, int n) {
  __shared__ float redp[4][128];
  __shared__ float sred[128];
  __shared__ float snorm[128];
  normReduce(partIn, al, ga, be, n, sred, snorm);
  const int lane = threadIdx.x & 63;
  const int wsl = threadIdx.x >> 6;
  const float sc = snorm[lane], sh = snorm[64 + lane];
  float s1 = 0.0f, s2 = 0.0f;
  const int wid = (blockIdx.x * blockDim.x + threadIdx.x) >> 6;
  const int nw = (gridDim.x * blockDim.x) >> 6;
  int base = wid * 4;
  const int stride = nw * 4;
  for (; base + 4 <= n; base += stride) {
    float f0 = feat[(size_t)(base + 0) * D64 + lane];
    float f1 = feat[(size_t)(base + 1) * D64 + lane];
    float f2 = feat[(size_t)(base + 2) * D64 + lane];
    float f3 = feat[(size_t)(base + 3) * D64 + lane];
    f0 = fmaf(f0, sc, sh);
    f1 = fmaf(f1, sc, sh);
    f2 = fmaf(f2, sc, sh);
    f3 = fmaf(f3, sc, sh);
    feat[(size_t)(base + 0) * D64 + lane] = f0;
    feat[(size_t)(base + 1) * D64 + lane] = f1;
    feat[(size_t)(base + 2) * D64 + lane] = f2;
    feat[(size_t)(base + 3) * D64 + lane] = f3;
    float e0 = expf(f0 - 20.0f);
    float e1 = expf(f1 - 20.0f);
    float e2 = expf(f2 - 20.0f);
    float e3 = expf(f3 - 20.0f);
    s1 += (e0 + e1) + (e2 + e3);
    s2 += fmaf(f0, e0, f1 * e1) + fmaf(f2, e2, f3 * e3);
  }
  for (int r = base; r < n; ++r) {
    float f = fmaf(feat[(size_t)r * D64 + lane], sc, sh);
    feat[(size_t)r * D64 + lane] = f;
    float e = expf(f - 20.0f);
    s1 += e;
    s2 += f * e;
  }
  redp[wsl][lane] = s1;
  redp[wsl][64 + lane] = s2;
  __syncthreads();
  if (threadIdx.x < 128) {
    float v = redp[0][threadIdx.x] + redp[1][threadIdx.x] +
              redp[2][threadIdx.x] + redp[3][threadIdx.x];
    atomAddF(&partOut[(blockIdx.x & 63) * 128 + threadIdx.x], v);
  }
}

// final reduce of striped pool partials -> pooled = s2/s1
__global__ void k_pooled(const float* __restrict__ part, float* __restrict__ out) {
  int d = threadIdx.x;  // 64 threads
  float s1 = 0.0f, s2 = 0.0f;
#pragma unroll 8
  for (int b = 0; b < 64; ++b) {
    s1 += part[b * 128 + d];
    s2 += part[b * 128 + 64 + d];
  }
  out[d] = s2 / s1;
}

extern "C" void kernel_launch(void* const* d_in, const int* in_sizes, int n_in,
                              void* d_out, int out_size, void* d_ws, size_t ws_size,
                              hipStream_t stream) {
  const int* z = (const int*)d_in[0];
  const int* src = (const int*)d_in[1];
  const int* dst = (const int*)d_in[2];
  const float* rij = (const float*)d_in[3];
  const float* emb = (const float*)d_in[4];
  const float* Win = (const float*)d_in[5];
  const float* Wf1 = (const float*)d_in[6];
  const float* bf1 = (const float*)d_in[7];
  const float* Wf2 = (const float*)d_in[8];
  const float* bf2 = (const float*)d_in[9];
  const float* Wo1 = (const float*)d_in[10];
  const float* bo1 = (const float*)d_in[11];
  const float* Wo2 = (const float*)d_in[12];
  const float* bo2 = (const float*)d_in[13];
  const float* gal = (const float*)d_in[14];
  const float* gga = (const float*)d_in[15];
  const float* gbe = (const float*)d_in[16];
  const int n = in_sizes[0];
  const int E = in_sizes[1];
  (void)n_in; (void)out_size; (void)ws_size;

  float* feat = (float*)d_out;                 // [n,64] lives in d_out
  float* pooled = feat + (size_t)n * D64;      // [64]

  char* w = (char*)d_ws;
  size_t off = 0;
  auto take = [&](size_t bytes) {
    size_t o = (off + 255) & ~(size_t)255;
    off = o + bytes;
    return (void*)(w + o);
  };
  __hip_bfloat16* x1 = (__hip_bfloat16*)take((size_t)n * D64 * 2);
  size_t aggrec = ((size_t)n * D64 * 2 > (size_t)E * 8) ? (size_t)n * D64 * 2
                                                        : (size_t)E * 8;
  unsigned short* aggb = (unsigned short*)take(aggrec);  // aliased with rec
  uint2* rec = (uint2*)aggb;
  float* part = (float*)take(4 * 64 * 128 * 4);   // 4 buffers: L0,L1,L2,pool
  __hip_bfloat16* Tb = (__hip_bfloat16*)take((size_t)3 * TROWS * D64 * 2);
  unsigned short* Wb = (unsigned short*)take((size_t)9 * 64 * 64 * 2);
  int* rp = (int*)take((size_t)(n + 1) * 4);
  unsigned* ep = (unsigned*)take((size_t)E * 4);
  int* misc = (int*)take((64 + 64 * 16) * 4);  // [0..63]=bcnt, [64..]=gcur (padded)
  int* bcnt = misc;
  int* gcur = misc + 64;

  const int total = n * D64;
  const int nbInit = (total + 255) / 256;

  hipMemsetAsync(misc, 0, (64 + 64 * 16) * 4, stream);
  hipMemsetAsync(part, 0, 4 * 64 * 128 * 4, stream);
  k_pre<<<nbInit + 18 + 256, 256, 0, stream>>>(z, emb, feat, Win, Wo1, Wo2, Wb,
                                               dst, bcnt, total, nbInit, E);
  k_ptab<<<PARTB + TABB, 1024, 0, stream>>>(src, dst, rij, bcnt, gcur, rec, E,
                                            Wf1, bf1, Wf2, bf2, Tb);
  k_build<<<256, 1024, 0, stream>>>(rec, bcnt, rp, ep, n);

  for (int l = 0; l < 3; ++l) {
    const float* pin = (l == 0) ? nullptr : part + (size_t)(l - 1) * 8192;
    const float* al = (l == 0) ? nullptr : gal + (l - 1) * D64;
    const float* ga = (l == 0) ? nullptr : gga + (l - 1) * D64;
    const float* be = (l == 0) ? nullptr : gbe + (l - 1) * D64;
    k_x1<<<784, 256, 0, stream>>>(feat, Wb + (size_t)(l * 3 + 0) * 64 * 64,
                                  pin, al, ga, be, x1, n);
    k_gather<<<2048, 256, 0, stream>>>(x1, Tb + (size_t)l * TROWS * D64,
                                       ep, rp, aggb, n);
    k_out<<<784, 256, 0, stream>>>(aggb,
                                   Wb + (size_t)(l * 3 + 1) * 64 * 64,
                                   Wb + (size_t)(l * 3 + 2) * 64 * 64,
                                   bo1 + l * D64, bo2 + l * D64,
                                   pin, al, ga, be,
                                   feat, part + (size_t)l * 8192, n);
  }

  k_pool<<<1024, 256, 0, stream>>>(feat, part + 2 * 8192,
                                   gal + 2 * D64, gga + 2 * D64, gbe + 2 * D64,
                                   part + 3 * 8192, n);
  k_pooled<<<1, 64, 0, stream>>>(part + 3 * 8192, pooled);
}